// Round 9
// baseline (173.420 us; speedup 1.0000x reference)
//
#include <hip/hip_runtime.h>

typedef __attribute__((ext_vector_type(8))) short  bf16x8;
typedef __attribute__((ext_vector_type(4))) float  f32x4;

#define S_LEN 4096
#define DH    64
#define NEGF  10000.0f

__device__ __forceinline__ unsigned short f2bf(float f) {
  unsigned u = __float_as_uint(f);
  u += 0x7FFF + ((u >> 16) & 1);          // RNE
  return (unsigned short)(u >> 16);
}

__device__ __forceinline__ bf16x8 pack8(float4 a, float4 b) {
  bf16x8 r;
  r[0] = (short)f2bf(a.x); r[1] = (short)f2bf(a.y);
  r[2] = (short)f2bf(a.z); r[3] = (short)f2bf(a.w);
  r[4] = (short)f2bf(b.x); r[5] = (short)f2bf(b.y);
  r[6] = (short)f2bf(b.z); r[7] = (short)f2bf(b.w);
  return r;
}

// XOR-swizzled byte offset in a [rows][64 bf16] row-major LDS tile (stride 128B)
__device__ __forceinline__ int swz(int row, int colb) {
  return (row << 7) + (colb ^ ((row & 7) << 4));
}

// 16 waves: q-group g = wid>>2 (16 rows each), KV phase r = wid&3.
// Register-double-buffered staging: loads for super-iter s+1 issue right
// after the "LDS ready" barrier and complete under compute of s (T14).
__global__ __launch_bounds__(1024, 1)
void attn_fwd(const float* __restrict__ Q, const float* __restrict__ K,
              const float* __restrict__ V, const int* __restrict__ Msk,
              float* __restrict__ O) {
  __shared__ __align__(16) unsigned char smem[98304];
  __shared__ int sfb;
  unsigned char* smK  = smem;           // 4 tiles x [64 k][64 d] bf16 swizzled (32KB)
  unsigned char* smVt = smem + 32768;   // 4 tiles x [64 d][64 k] bf16 swizzled (32KB)
  unsigned char* smP  = smem + 65536;   // 16 waves x [16 q][64 k] bf16 swizzled (32KB)

  const int tid  = threadIdx.x;
  const int lane = tid & 63;
  const int wid  = tid >> 6;
  const int g    = wid >> 2;    // q-row group (0..3)
  const int r    = wid & 3;     // KV phase   (0..3)
  const int p    = lane & 15;
  const int h    = lane >> 4;

  const int b  = blockIdx.x >> 6;
  const int qt = blockIdx.x & 63;
  const int q0 = qt << 6;

  const float* Qb = Q + ((size_t)b * S_LEN) * DH;
  const float* Kb = K + ((size_t)b * S_LEN) * DH;
  const float* Vb = V + ((size_t)b * S_LEN) * DH;
  const int*   Mb = Msk + b * S_LEN;

  // staging decomposition (constant per thread)
  const int k_row0 = tid >> 3;            // 0..127 (tile = k_row0>>6, row = &63)
  const int k_colf = (tid & 7) << 3;      // d col 0..56
  const int v_dcol = tid & 63;
  const int v_kc0  = tid >> 6;            // 0..15 (tile = v_kc0>>3, kc = &7)

  // prefetch register buffers
  float4 pk[2][2];
  float  pv[2][8];
  int    pm[4];

  auto PREFETCH = [&](int s) {
    const int kb4 = s << 2;
#pragma unroll
    for (int cc = 0; cc < 2; ++cc) {
      const int rr256 = k_row0 + (cc << 7);          // 0..255
      const int kt = rr256 >> 6, krow = rr256 & 63;
      if (kb4 + kt <= qt) {
        const float4* kp =
            (const float4*)(Kb + (size_t)((kb4 + kt) * 64 + krow) * DH + k_colf);
        pk[cc][0] = kp[0]; pk[cc][1] = kp[1];
      }
      const int kc16 = v_kc0 + (cc << 4);            // 0..31
      const int vt = kc16 >> 3, vkc = kc16 & 7;
      if (kb4 + vt <= qt) {
#pragma unroll
        for (int e = 0; e < 8; ++e)
          pv[cc][e] = Vb[(size_t)((kb4 + vt) * 64 + vkc * 8 + e) * DH + v_dcol];
      }
    }
    const int j = kb4 + r;
    if (j <= qt) {
#pragma unroll
      for (int t16 = 0; t16 < 4; ++t16)
        pm[t16] = Mb[(j << 6) + t16 * 16 + p];
    }
  };

  auto WRITE_LDS = [&](int s) {
    const int kb4 = s << 2;
#pragma unroll
    for (int cc = 0; cc < 2; ++cc) {
      const int rr256 = k_row0 + (cc << 7);
      const int kt = rr256 >> 6, krow = rr256 & 63;
      if (kb4 + kt <= qt)
        *(bf16x8*)(smK + kt * 8192 + swz(krow, k_colf << 1)) =
            pack8(pk[cc][0], pk[cc][1]);
      const int kc16 = v_kc0 + (cc << 4);
      const int vt = kc16 >> 3, vkc = kc16 & 7;
      if (kb4 + vt <= qt) {
        bf16x8 vp;
#pragma unroll
        for (int e = 0; e < 8; ++e) vp[e] = (short)f2bf(pv[cc][e]);
        *(bf16x8*)(smVt + vt * 8192 + swz(v_dcol, vkc << 4)) = vp;
      }
    }
  };

  // ---- fb = min{k : mask[b,k]=1} (block-uniform) ----
  if (tid == 0) sfb = S_LEN;
  __syncthreads();
  PREFETCH(0);
  {
    int loc = S_LEN;
    for (int k = tid; k < S_LEN; k += 1024)
      if (Mb[k]) { loc = k; break; }
    if (loc < S_LEN) atomicMin(&sfb, loc);
  }
  __syncthreads();
  const int fb = sfb;

  // ---- Q fragments (A operand: row = lane&15; slots = contiguous d) ----
  bf16x8 qf[2];
  {
    const float* qp = Qb + (size_t)(q0 + g * 16 + p) * DH + h * 8;
    const float4* q4a = (const float4*)(qp);
    const float4* q4b = (const float4*)(qp + 32);
    qf[0] = pack8(q4a[0], q4a[1]);
    qf[1] = pack8(q4b[0], q4b[1]);
  }

  f32x4 o[4];
  float m_r[4], l_r[4];
#pragma unroll
  for (int j = 0; j < 4; ++j)
#pragma unroll
    for (int e = 0; e < 4; ++e) o[j][e] = 0.f;
#pragma unroll
  for (int rr = 0; rr < 4; ++rr) { m_r[rr] = -INFINITY; l_r[rr] = 0.f; }

  const int qrb = q0 + g * 16 + h * 4;  // + rr => this lane's acc rows

  const int ns = (qt >> 2) + 1;         // ceil((qt+1)/4)
  for (int s = 0; s < ns; ++s) {
    __syncthreads();                    // (a) LDS free; drains prefetch vmem
    WRITE_LDS(s);
    const int j = (s << 2) + r;         // this wave's KV tile
    float pen[4];
#pragma unroll
    for (int t16 = 0; t16 < 4; ++t16)
      pen[t16] = pm[t16] ? 0.f : -NEGF; // consume pm before next PREFETCH
    __syncthreads();                    // (b) LDS ready
    if (s + 1 < ns) PREFETCH(s + 1);    // loads fly during compute below

    if (j <= qt) {
      const int kv0 = j << 6;
      const unsigned char* myK  = smK  + r * 8192;
      const unsigned char* myVt = smVt + r * 8192;

      // ---- QK^T ----
      f32x4 acc[4];
#pragma unroll
      for (int t16 = 0; t16 < 4; ++t16) {
        f32x4 a;
#pragma unroll
        for (int e = 0; e < 4; ++e) a[e] = 0.f;
#pragma unroll
        for (int c = 0; c < 2; ++c) {
          bf16x8 kb = *(const bf16x8*)(myK + swz(t16 * 16 + p, c * 64 + h * 16));
          a = __builtin_amdgcn_mfma_f32_16x16x32_bf16(qf[c], kb, a, 0, 0, 0);
        }
        acc[t16] = a;
      }

      // ---- scores ----
      float sc[4][4];
#pragma unroll
      for (int t16 = 0; t16 < 4; ++t16) {
        const int key = kv0 + t16 * 16 + p;
#pragma unroll
        for (int rr = 0; rr < 4; ++rr) {
          float v = fmaf(acc[t16][rr], 0.125f, pen[t16]);
          if (key > qrb + rr) v -= NEGF;          // causal
          sc[t16][rr] = v;
        }
      }

      // ---- online softmax (phase-local partial) ----
      float alpha[4];
#pragma unroll
      for (int rr = 0; rr < 4; ++rr) {
        float v = fmaxf(fmaxf(sc[0][rr], sc[1][rr]), fmaxf(sc[2][rr], sc[3][rr]));
        v = fmaxf(v, __shfl_xor(v, 1));
        v = fmaxf(v, __shfl_xor(v, 2));
        v = fmaxf(v, __shfl_xor(v, 4));
        v = fmaxf(v, __shfl_xor(v, 8));
        const float mn = fmaxf(m_r[rr], v);
        alpha[rr] = __expf(m_r[rr] - mn);
        m_r[rr] = mn;
      }

      unsigned char* Pw = smP + (wid << 11);
      float rs[4] = {0.f, 0.f, 0.f, 0.f};
#pragma unroll
      for (int t16 = 0; t16 < 4; ++t16) {
#pragma unroll
        for (int rr = 0; rr < 4; ++rr) {
          float pv2 = __expf(sc[t16][rr] - m_r[rr]);
          rs[rr] += pv2;
          *(unsigned short*)(Pw + swz(h * 4 + rr, (t16 * 16 + p) << 1)) = f2bf(pv2);
        }
      }
#pragma unroll
      for (int rr = 0; rr < 4; ++rr) {
        float v = rs[rr];
        v += __shfl_xor(v, 1);
        v += __shfl_xor(v, 2);
        v += __shfl_xor(v, 4);
        v += __shfl_xor(v, 8);
        l_r[rr] = l_r[rr] * alpha[rr] + v;
      }
#pragma unroll
      for (int jj = 0; jj < 4; ++jj)
#pragma unroll
        for (int rr = 0; rr < 4; ++rr) o[jj][rr] *= alpha[rr];

      // same-wave P write -> P read: drain LDS, keep reads below
      asm volatile("s_waitcnt lgkmcnt(0)" ::: "memory");
      __builtin_amdgcn_sched_barrier(0);

      // ---- PV ----
      bf16x8 pf[2];
#pragma unroll
      for (int c = 0; c < 2; ++c)
        pf[c] = *(const bf16x8*)(Pw + swz(p, c * 64 + h * 16));
#pragma unroll
      for (int jj = 0; jj < 4; ++jj)
#pragma unroll
        for (int c = 0; c < 2; ++c) {
          bf16x8 vb = *(const bf16x8*)(myVt + swz(jj * 16 + p, c * 64 + h * 16));
          o[jj] = __builtin_amdgcn_mfma_f32_16x16x32_bf16(pf[c], vb, o[jj], 0, 0, 0);
        }
    }
  }

  // ---- merge 4 phase-partials per q-group. Layout [elem][wid][lane]:
  // lane-stride 4B -> conflict-free scalar stores/loads.
  __syncthreads();                       // all compute done; smem reusable
  {
    float* wb = (float*)smem + wid * 64 + lane;
#pragma unroll
    for (int rr = 0; rr < 4; ++rr) {
      wb[(rr)     * 1024] = m_r[rr];
      wb[(4 + rr) * 1024] = l_r[rr];
    }
#pragma unroll
    for (int jj = 0; jj < 4; ++jj)
#pragma unroll
      for (int rr = 0; rr < 4; ++rr)
        wb[(8 + jj * 4 + rr) * 1024] = o[jj][rr];
  }
  __syncthreads();

  if (r == 0) {
    const float* w0 = (float*)smem + (wid + 0) * 64 + lane;
    const float* w1 = (float*)smem + (wid + 1) * 64 + lane;
    const float* w2 = (float*)smem + (wid + 2) * 64 + lane;
    const float* w3 = (float*)smem + (wid + 3) * 64 + lane;
    float* Ob = O + ((size_t)b * S_LEN) * DH;
#pragma unroll
    for (int rr = 0; rr < 4; ++rr) {
      if (qrb + rr < fb) continue;       // degen row: written below
      const float M = fmaxf(fmaxf(w0[rr * 1024], w1[rr * 1024]),
                            fmaxf(w2[rr * 1024], w3[rr * 1024]));
      const float e0 = __expf(w0[rr * 1024] - M), e1 = __expf(w1[rr * 1024] - M);
      const float e2 = __expf(w2[rr * 1024] - M), e3 = __expf(w3[rr * 1024] - M);
      const float L = w0[(4 + rr) * 1024] * e0 + w1[(4 + rr) * 1024] * e1 +
                      w2[(4 + rr) * 1024] * e2 + w3[(4 + rr) * 1024] * e3;
      const float inv = 1.f / L;
#pragma unroll
      for (int jj = 0; jj < 4; ++jj) {
        const int e = (8 + jj * 4 + rr) * 1024;
        const float num = w0[e] * e0 + w1[e] * e1 + w2[e] * e2 + w3[e] * e3;
        Ob[(size_t)(qrb + rr) * DH + jj * 16 + p] = num * inv;
      }
    }
  }

  // ---- degenerate rows: q ≡ qt (mod 64), q < fb ----
  for (int dq = qt; dq < fb; dq += 64) {
    __syncthreads();                     // merge reads done; smem reusable
    float* ssc   = (float*)smem;         // [4096] exp-scores
    float* sq    = (float*)smem + 4096;  // [64] q-vector
    float* spart = (float*)smem + 4160;  // [16][64] wave PV partials
    float* sred  = (float*)smem + 5184;  // [32] reduction scratch
    if (tid < 64) sq[tid] = Qb[(size_t)dq * DH + tid];
    __syncthreads();

    float lmax = -1e30f;
    for (int k = tid; k < S_LEN; k += 1024) {
      float s = -1e30f;
      if (k <= dq || Mb[k]) {
        const float4* kp = (const float4*)(Kb + (size_t)k * DH);
        float acc = 0.f;
#pragma unroll
        for (int d4 = 0; d4 < 16; ++d4) {
          const float4 kv = kp[d4];
          acc += sq[d4 * 4 + 0] * kv.x + sq[d4 * 4 + 1] * kv.y +
                 sq[d4 * 4 + 2] * kv.z + sq[d4 * 4 + 3] * kv.w;
        }
        s = acc * 0.125f;
      }
      ssc[k] = s;
      lmax = fmaxf(lmax, s);
    }
#pragma unroll
    for (int o2 = 32; o2; o2 >>= 1) lmax = fmaxf(lmax, __shfl_xor(lmax, o2));
    if (lane == 0) sred[wid] = lmax;
    __syncthreads();
    float gmax = sred[0];
#pragma unroll
    for (int i = 1; i < 16; ++i) gmax = fmaxf(gmax, sred[i]);

    float lsum = 0.f;
    for (int k = tid; k < S_LEN; k += 1024) {
      const float e = (ssc[k] > -1e29f) ? __expf(ssc[k] - gmax) : 0.f;
      ssc[k] = e;
      lsum += e;
    }
#pragma unroll
    for (int o2 = 32; o2; o2 >>= 1) lsum += __shfl_xor(lsum, o2);
    if (lane == 0) sred[16 + wid] = lsum;
    __syncthreads();
    float gsum = 0.f;
#pragma unroll
    for (int i = 0; i < 16; ++i) gsum += sred[16 + i];
    const float inv = 1.f / gsum;

    {
      const int k0d = wid << 8;
      float a0 = 0.f, a1 = 0.f, a2 = 0.f, a3 = 0.f;
      for (int kk = 0; kk < 256; kk += 4) {
        a0 = fmaf(ssc[k0d + kk + 0], Vb[(size_t)(k0d + kk + 0) * DH + lane], a0);
        a1 = fmaf(ssc[k0d + kk + 1], Vb[(size_t)(k0d + kk + 1) * DH + lane], a1);
        a2 = fmaf(ssc[k0d + kk + 2], Vb[(size_t)(k0d + kk + 2) * DH + lane], a2);
        a3 = fmaf(ssc[k0d + kk + 3], Vb[(size_t)(k0d + kk + 3) * DH + lane], a3);
      }
      spart[wid * 64 + lane] = (a0 + a1) + (a2 + a3);
    }
    __syncthreads();
    if (tid < 64) {
      float num = 0.f;
#pragma unroll
      for (int i = 0; i < 16; ++i) num += spart[i * 64 + tid];
      O[((size_t)b * S_LEN + dq) * DH + tid] = num * inv;
    }
  }
}

extern "C" void kernel_launch(void* const* d_in, const int* in_sizes, int n_in,
                              void* d_out, int out_size, void* d_ws, size_t ws_size,
                              hipStream_t stream) {
  const float* Q = (const float*)d_in[0];
  const float* K = (const float*)d_in[1];
  const float* V = (const float*)d_in[2];
  const int*   M = (const int*)d_in[3];
  float* O = (float*)d_out;
  attn_fwd<<<dim3(4 * (S_LEN / 64)), dim3(1024), 0, stream>>>(Q, K, V, M, O);
}

// Round 10
// 159.213 us; speedup vs baseline: 1.0892x; 1.0892x over previous
//
#include <hip/hip_runtime.h>

typedef __attribute__((ext_vector_type(8))) short  bf16x8;
typedef __attribute__((ext_vector_type(4))) float  f32x4;

#define S_LEN 4096
#define DH    64
#define NEGF  10000.0f

__device__ __forceinline__ unsigned short f2bf(float f) {
  unsigned u = __float_as_uint(f);
  u += 0x7FFF + ((u >> 16) & 1);          // RNE
  return (unsigned short)(u >> 16);
}

__device__ __forceinline__ bf16x8 pack8(float4 a, float4 b) {
  bf16x8 r;
  r[0] = (short)f2bf(a.x); r[1] = (short)f2bf(a.y);
  r[2] = (short)f2bf(a.z); r[3] = (short)f2bf(a.w);
  r[4] = (short)f2bf(b.x); r[5] = (short)f2bf(b.y);
  r[6] = (short)f2bf(b.z); r[7] = (short)f2bf(b.w);
  return r;
}

// XOR-swizzled byte offset in a [rows][64 bf16] row-major LDS tile (stride 128B)
__device__ __forceinline__ int swz(int row, int colb) {
  return (row << 7) + (colb ^ ((row & 7) << 4));
}

// 16 waves: q-group g = wid>>2 (16 rows each), KV phase r = wid&3.
// Register-double-buffered staging (T14). __launch_bounds__(1024,4): a
// 16-wave block is 4 waves/SIMD -> VGPR cap 128; (1024,1) made the compiler
// cap at 64 and spill the ~36 prefetch regs (R9: WRITE_SIZE 8x = scratch).
__global__ __launch_bounds__(1024, 4)
void attn_fwd(const float* __restrict__ Q, const float* __restrict__ K,
              const float* __restrict__ V, const int* __restrict__ Msk,
              float* __restrict__ O) {
  __shared__ __align__(16) unsigned char smem[98304];
  __shared__ int sfb;
  unsigned char* smK  = smem;           // 4 tiles x [64 k][64 d] bf16 swizzled (32KB)
  unsigned char* smVt = smem + 32768;   // 4 tiles x [64 d][64 k] bf16 swizzled (32KB)
  unsigned char* smP  = smem + 65536;   // 16 waves x [16 q][64 k] bf16 swizzled (32KB)

  const int tid  = threadIdx.x;
  const int lane = tid & 63;
  const int wid  = tid >> 6;
  const int g    = wid >> 2;    // q-row group (0..3)
  const int r    = wid & 3;     // KV phase   (0..3)
  const int p    = lane & 15;
  const int h    = lane >> 4;

  const int b  = blockIdx.x >> 6;
  const int qt = blockIdx.x & 63;
  const int q0 = qt << 6;

  const float* Qb = Q + ((size_t)b * S_LEN) * DH;
  const float* Kb = K + ((size_t)b * S_LEN) * DH;
  const float* Vb = V + ((size_t)b * S_LEN) * DH;
  const int*   Mb = Msk + b * S_LEN;

  // staging decomposition (constant per thread)
  const int k_row0 = tid >> 3;            // 0..127
  const int k_colf = (tid & 7) << 3;      // d col 0..56
  const int v_dcol = tid & 63;
  const int v_kc0  = tid >> 6;            // 0..15

  // prefetch register buffers (always loaded; addresses clamped to S_LEN-1,
  // garbage lands in LDS tiles that are never read)
  float4 pk[2][2];
  float  pv[2][8];
  int    pm[4];

  auto PREFETCH = [&](int s) {
    const int kb4r = s << 8;              // first kv ROW of this super-iter
#pragma unroll
    for (int cc = 0; cc < 2; ++cc) {
      const int krow = min(kb4r + k_row0 + (cc << 7), S_LEN - 1);
      const float4* kp = (const float4*)(Kb + (size_t)krow * DH + k_colf);
      pk[cc][0] = kp[0]; pk[cc][1] = kp[1];
      const int vbase = kb4r + (v_kc0 + (cc << 4)) * 8;
#pragma unroll
      for (int e = 0; e < 8; ++e)
        pv[cc][e] = Vb[(size_t)min(vbase + e, S_LEN - 1) * DH + v_dcol];
    }
    const int j = min((s << 2) + r, qt);
#pragma unroll
    for (int t16 = 0; t16 < 4; ++t16)
      pm[t16] = Mb[(j << 6) + t16 * 16 + p];
  };

  auto WRITE_LDS = [&]() {
#pragma unroll
    for (int cc = 0; cc < 2; ++cc) {
      const int rr256 = k_row0 + (cc << 7);
      const int kt = rr256 >> 6, krow = rr256 & 63;
      *(bf16x8*)(smK + kt * 8192 + swz(krow, k_colf << 1)) =
          pack8(pk[cc][0], pk[cc][1]);
      const int kc16 = v_kc0 + (cc << 4);
      const int vt = kc16 >> 3, vkc = kc16 & 7;
      bf16x8 vp;
#pragma unroll
      for (int e = 0; e < 8; ++e) vp[e] = (short)f2bf(pv[cc][e]);
      *(bf16x8*)(smVt + vt * 8192 + swz(v_dcol, vkc << 4)) = vp;
    }
  };

  // ---- fb = min{k : mask[b,k]=1} (block-uniform) ----
  if (tid == 0) sfb = S_LEN;
  __syncthreads();
  PREFETCH(0);
  {
    int loc = S_LEN;
    for (int k = tid; k < S_LEN; k += 1024)
      if (Mb[k]) { loc = k; break; }
    if (loc < S_LEN) atomicMin(&sfb, loc);
  }
  __syncthreads();
  const int fb = sfb;

  // ---- Q fragments (A operand: row = lane&15; slots = contiguous d) ----
  bf16x8 qf[2];
  {
    const float* qp = Qb + (size_t)(q0 + g * 16 + p) * DH + h * 8;
    const float4* q4a = (const float4*)(qp);
    const float4* q4b = (const float4*)(qp + 32);
    qf[0] = pack8(q4a[0], q4a[1]);
    qf[1] = pack8(q4b[0], q4b[1]);
  }

  f32x4 o[4];
  float m_r[4], l_r[4];
#pragma unroll
  for (int j = 0; j < 4; ++j)
#pragma unroll
    for (int e = 0; e < 4; ++e) o[j][e] = 0.f;
#pragma unroll
  for (int rr = 0; rr < 4; ++rr) { m_r[rr] = -INFINITY; l_r[rr] = 0.f; }

  const int qrb = q0 + g * 16 + h * 4;  // + rr => this lane's acc rows

  const int ns = (qt >> 2) + 1;         // ceil((qt+1)/4)
  for (int s = 0; s < ns; ++s) {
    __syncthreads();                    // (a) LDS free
    WRITE_LDS();
    const int j = (s << 2) + r;         // this wave's KV tile
    float pen[4];
#pragma unroll
    for (int t16 = 0; t16 < 4; ++t16)
      pen[t16] = pm[t16] ? 0.f : -NEGF; // consume pm before next PREFETCH
    __syncthreads();                    // (b) LDS ready
    if (s + 1 < ns) PREFETCH(s + 1);    // loads fly during compute below

    if (j <= qt) {
      const int kv0 = j << 6;
      const unsigned char* myK  = smK  + r * 8192;
      const unsigned char* myVt = smVt + r * 8192;

      // ---- QK^T ----
      f32x4 acc[4];
#pragma unroll
      for (int t16 = 0; t16 < 4; ++t16) {
        f32x4 a;
#pragma unroll
        for (int e = 0; e < 4; ++e) a[e] = 0.f;
#pragma unroll
        for (int c = 0; c < 2; ++c) {
          bf16x8 kb = *(const bf16x8*)(myK + swz(t16 * 16 + p, c * 64 + h * 16));
          a = __builtin_amdgcn_mfma_f32_16x16x32_bf16(qf[c], kb, a, 0, 0, 0);
        }
        acc[t16] = a;
      }

      // ---- scores ----
      float sc[4][4];
#pragma unroll
      for (int t16 = 0; t16 < 4; ++t16) {
        const int key = kv0 + t16 * 16 + p;
#pragma unroll
        for (int rr = 0; rr < 4; ++rr) {
          float v = fmaf(acc[t16][rr], 0.125f, pen[t16]);
          if (key > qrb + rr) v -= NEGF;          // causal
          sc[t16][rr] = v;
        }
      }

      // ---- online softmax (phase-local partial) ----
      float alpha[4];
#pragma unroll
      for (int rr = 0; rr < 4; ++rr) {
        float v = fmaxf(fmaxf(sc[0][rr], sc[1][rr]), fmaxf(sc[2][rr], sc[3][rr]));
        v = fmaxf(v, __shfl_xor(v, 1));
        v = fmaxf(v, __shfl_xor(v, 2));
        v = fmaxf(v, __shfl_xor(v, 4));
        v = fmaxf(v, __shfl_xor(v, 8));
        const float mn = fmaxf(m_r[rr], v);
        alpha[rr] = __expf(m_r[rr] - mn);
        m_r[rr] = mn;
      }

      unsigned char* Pw = smP + (wid << 11);
      float rs[4] = {0.f, 0.f, 0.f, 0.f};
#pragma unroll
      for (int t16 = 0; t16 < 4; ++t16) {
#pragma unroll
        for (int rr = 0; rr < 4; ++rr) {
          float pv2 = __expf(sc[t16][rr] - m_r[rr]);
          rs[rr] += pv2;
          *(unsigned short*)(Pw + swz(h * 4 + rr, (t16 * 16 + p) << 1)) = f2bf(pv2);
        }
      }
#pragma unroll
      for (int rr = 0; rr < 4; ++rr) {
        float v = rs[rr];
        v += __shfl_xor(v, 1);
        v += __shfl_xor(v, 2);
        v += __shfl_xor(v, 4);
        v += __shfl_xor(v, 8);
        l_r[rr] = l_r[rr] * alpha[rr] + v;
      }
#pragma unroll
      for (int jj = 0; jj < 4; ++jj)
#pragma unroll
        for (int rr = 0; rr < 4; ++rr) o[jj][rr] *= alpha[rr];

      // same-wave P write -> P read: drain LDS, keep reads below
      asm volatile("s_waitcnt lgkmcnt(0)" ::: "memory");
      __builtin_amdgcn_sched_barrier(0);

      // ---- PV ----
      bf16x8 pf[2];
#pragma unroll
      for (int c = 0; c < 2; ++c)
        pf[c] = *(const bf16x8*)(Pw + swz(p, c * 64 + h * 16));
#pragma unroll
      for (int jj = 0; jj < 4; ++jj)
#pragma unroll
        for (int c = 0; c < 2; ++c) {
          bf16x8 vb = *(const bf16x8*)(myVt + swz(jj * 16 + p, c * 64 + h * 16));
          o[jj] = __builtin_amdgcn_mfma_f32_16x16x32_bf16(pf[c], vb, o[jj], 0, 0, 0);
        }
    }
  }

  // ---- merge 4 phase-partials per q-group. Layout [elem][wid][lane]:
  // lane-stride 4B -> conflict-free scalar stores/loads.
  __syncthreads();                       // all compute done; smem reusable
  {
    float* wb = (float*)smem + wid * 64 + lane;
#pragma unroll
    for (int rr = 0; rr < 4; ++rr) {
      wb[(rr)     * 1024] = m_r[rr];
      wb[(4 + rr) * 1024] = l_r[rr];
    }
#pragma unroll
    for (int jj = 0; jj < 4; ++jj)
#pragma unroll
      for (int rr = 0; rr < 4; ++rr)
        wb[(8 + jj * 4 + rr) * 1024] = o[jj][rr];
  }
  __syncthreads();

  if (r == 0) {
    const float* w0 = (float*)smem + (wid + 0) * 64 + lane;
    const float* w1 = (float*)smem + (wid + 1) * 64 + lane;
    const float* w2 = (float*)smem + (wid + 2) * 64 + lane;
    const float* w3 = (float*)smem + (wid + 3) * 64 + lane;
    float* Ob = O + ((size_t)b * S_LEN) * DH;
#pragma unroll
    for (int rr = 0; rr < 4; ++rr) {
      if (qrb + rr < fb) continue;       // degen row: written below
      const float M = fmaxf(fmaxf(w0[rr * 1024], w1[rr * 1024]),
                            fmaxf(w2[rr * 1024], w3[rr * 1024]));
      const float e0 = __expf(w0[rr * 1024] - M), e1 = __expf(w1[rr * 1024] - M);
      const float e2 = __expf(w2[rr * 1024] - M), e3 = __expf(w3[rr * 1024] - M);
      const float L = w0[(4 + rr) * 1024] * e0 + w1[(4 + rr) * 1024] * e1 +
                      w2[(4 + rr) * 1024] * e2 + w3[(4 + rr) * 1024] * e3;
      const float inv = 1.f / L;
#pragma unroll
      for (int jj = 0; jj < 4; ++jj) {
        const int e = (8 + jj * 4 + rr) * 1024;
        const float num = w0[e] * e0 + w1[e] * e1 + w2[e] * e2 + w3[e] * e3;
        Ob[(size_t)(qrb + rr) * DH + jj * 16 + p] = num * inv;
      }
    }
  }

  // ---- degenerate rows: q ≡ qt (mod 64), q < fb ----
  for (int dq = qt; dq < fb; dq += 64) {
    __syncthreads();                     // merge reads done; smem reusable
    float* ssc   = (float*)smem;         // [4096] exp-scores
    float* sq    = (float*)smem + 4096;  // [64] q-vector
    float* spart = (float*)smem + 4160;  // [16][64] wave PV partials
    float* sred  = (float*)smem + 5184;  // [32] reduction scratch
    if (tid < 64) sq[tid] = Qb[(size_t)dq * DH + tid];
    __syncthreads();

    float lmax = -1e30f;
    for (int k = tid; k < S_LEN; k += 1024) {
      float s = -1e30f;
      if (k <= dq || Mb[k]) {
        const float4* kp = (const float4*)(Kb + (size_t)k * DH);
        float acc = 0.f;
#pragma unroll
        for (int d4 = 0; d4 < 16; ++d4) {
          const float4 kv = kp[d4];
          acc += sq[d4 * 4 + 0] * kv.x + sq[d4 * 4 + 1] * kv.y +
                 sq[d4 * 4 + 2] * kv.z + sq[d4 * 4 + 3] * kv.w;
        }
        s = acc * 0.125f;
      }
      ssc[k] = s;
      lmax = fmaxf(lmax, s);
    }
#pragma unroll
    for (int o2 = 32; o2; o2 >>= 1) lmax = fmaxf(lmax, __shfl_xor(lmax, o2));
    if (lane == 0) sred[wid] = lmax;
    __syncthreads();
    float gmax = sred[0];
#pragma unroll
    for (int i = 1; i < 16; ++i) gmax = fmaxf(gmax, sred[i]);

    float lsum = 0.f;
    for (int k = tid; k < S_LEN; k += 1024) {
      const float e = (ssc[k] > -1e29f) ? __expf(ssc[k] - gmax) : 0.f;
      ssc[k] = e;
      lsum += e;
    }
#pragma unroll
    for (int o2 = 32; o2; o2 >>= 1) lsum += __shfl_xor(lsum, o2);
    if (lane == 0) sred[16 + wid] = lsum;
    __syncthreads();
    float gsum = 0.f;
#pragma unroll
    for (int i = 0; i < 16; ++i) gsum += sred[16 + i];
    const float inv = 1.f / gsum;

    {
      const int k0d = wid << 8;
      float a0 = 0.f, a1 = 0.f, a2 = 0.f, a3 = 0.f;
      for (int kk = 0; kk < 256; kk += 4) {
        a0 = fmaf(ssc[k0d + kk + 0], Vb[(size_t)(k0d + kk + 0) * DH + lane], a0);
        a1 = fmaf(ssc[k0d + kk + 1], Vb[(size_t)(k0d + kk + 1) * DH + lane], a1);
        a2 = fmaf(ssc[k0d + kk + 2], Vb[(size_t)(k0d + kk + 2) * DH + lane], a2);
        a3 = fmaf(ssc[k0d + kk + 3], Vb[(size_t)(k0d + kk + 3) * DH + lane], a3);
      }
      spart[wid * 64 + lane] = (a0 + a1) + (a2 + a3);
    }
    __syncthreads();
    if (tid < 64) {
      float num = 0.f;
#pragma unroll
      for (int i = 0; i < 16; ++i) num += spart[i * 64 + tid];
      O[((size_t)b * S_LEN + dq) * DH + tid] = num * inv;
    }
  }
}

extern "C" void kernel_launch(void* const* d_in, const int* in_sizes, int n_in,
                              void* d_out, int out_size, void* d_ws, size_t ws_size,
                              hipStream_t stream) {
  const float* Q = (const float*)d_in[0];
  const float* K = (const float*)d_in[1];
  const float* V = (const float*)d_in[2];
  const int*   M = (const int*)d_in[3];
  float* O = (float*)d_out;
  attn_fwd<<<dim3(4 * (S_LEN / 64)), dim3(1024), 0, stream>>>(Q, K, V, M, O);
}

// Round 11
// 158.139 us; speedup vs baseline: 1.0966x; 1.0068x over previous
//
#include <hip/hip_runtime.h>

typedef __attribute__((ext_vector_type(8))) short  bf16x8;
typedef __attribute__((ext_vector_type(4))) float  f32x4;

#define S_LEN 4096
#define DH    64
#define NEGF  10000.0f

__device__ __forceinline__ unsigned short f2bf(float f) {
  unsigned u = __float_as_uint(f);
  u += 0x7FFF + ((u >> 16) & 1);          // RNE
  return (unsigned short)(u >> 16);
}

__device__ __forceinline__ bf16x8 pack8(float4 a, float4 b) {
  bf16x8 r;
  r[0] = (short)f2bf(a.x); r[1] = (short)f2bf(a.y);
  r[2] = (short)f2bf(a.z); r[3] = (short)f2bf(a.w);
  r[4] = (short)f2bf(b.x); r[5] = (short)f2bf(b.y);
  r[6] = (short)f2bf(b.z); r[7] = (short)f2bf(b.w);
  return r;
}

// XOR-swizzled byte offset in a [rows][64 bf16] row-major LDS tile (stride 128B)
__device__ __forceinline__ int swz(int row, int colb) {
  return (row << 7) + (colb ^ ((row & 7) << 4));
}

// 16 waves: q-group g = wid>>2 (16 rows each), KV phase r = wid&3.
// Register-double-buffered staging (T14). 96KB LDS -> exactly 1 block/CU =
// 4 waves/EU; amdgpu_waves_per_eu(4,4) pins the regalloc target there so it
// may use ~128 VGPRs. R9/R10: launch_bounds alone left the heuristic at 64
// VGPR -> prefetch regs spilled to scratch (WRITE_SIZE 8x) and the spill
// stores made the prefetch synchronous.
__global__ __launch_bounds__(1024, 4) __attribute__((amdgpu_waves_per_eu(4, 4)))
void attn_fwd(const float* __restrict__ Q, const float* __restrict__ K,
              const float* __restrict__ V, const int* __restrict__ Msk,
              float* __restrict__ O) {
  __shared__ __align__(16) unsigned char smem[98304];
  __shared__ int sfb;
  unsigned char* smK  = smem;           // 4 tiles x [64 k][64 d] bf16 swizzled (32KB)
  unsigned char* smVt = smem + 32768;   // 4 tiles x [64 d][64 k] bf16 swizzled (32KB)
  unsigned char* smP  = smem + 65536;   // 16 waves x [16 q][64 k] bf16 swizzled (32KB)

  const int tid  = threadIdx.x;
  const int lane = tid & 63;
  const int wid  = tid >> 6;
  const int g    = wid >> 2;    // q-row group (0..3)
  const int r    = wid & 3;     // KV phase   (0..3)
  const int p    = lane & 15;
  const int h    = lane >> 4;

  const int b  = blockIdx.x >> 6;
  const int qt = blockIdx.x & 63;
  const int q0 = qt << 6;

  const float* Qb = Q + ((size_t)b * S_LEN) * DH;
  const float* Kb = K + ((size_t)b * S_LEN) * DH;
  const float* Vb = V + ((size_t)b * S_LEN) * DH;
  const int*   Mb = Msk + b * S_LEN;

  // staging decomposition (constant per thread)
  const int k_row0 = tid >> 3;            // 0..127
  const int k_colf = (tid & 7) << 3;      // d col 0..56
  const int v_dcol = tid & 63;
  const int v_kc0  = tid >> 6;            // 0..15

  // prefetch register buffers (always loaded; addresses clamped to S_LEN-1,
  // garbage lands in LDS tiles that are never read)
  float4 pk[2][2];
  float  pv[2][8];
  int    pm[4];

  auto PREFETCH = [&](int s) {
    const int kb4r = s << 8;              // first kv ROW of this super-iter
#pragma unroll
    for (int cc = 0; cc < 2; ++cc) {
      const int krow = min(kb4r + k_row0 + (cc << 7), S_LEN - 1);
      const float4* kp = (const float4*)(Kb + (size_t)krow * DH + k_colf);
      pk[cc][0] = kp[0]; pk[cc][1] = kp[1];
      const int vbase = kb4r + (v_kc0 + (cc << 4)) * 8;
#pragma unroll
      for (int e = 0; e < 8; ++e)
        pv[cc][e] = Vb[(size_t)min(vbase + e, S_LEN - 1) * DH + v_dcol];
    }
    const int j = min((s << 2) + r, qt);
#pragma unroll
    for (int t16 = 0; t16 < 4; ++t16)
      pm[t16] = Mb[(j << 6) + t16 * 16 + p];
  };

  auto WRITE_LDS = [&]() {
#pragma unroll
    for (int cc = 0; cc < 2; ++cc) {
      const int rr256 = k_row0 + (cc << 7);
      const int kt = rr256 >> 6, krow = rr256 & 63;
      *(bf16x8*)(smK + kt * 8192 + swz(krow, k_colf << 1)) =
          pack8(pk[cc][0], pk[cc][1]);
      const int kc16 = v_kc0 + (cc << 4);
      const int vt = kc16 >> 3, vkc = kc16 & 7;
      bf16x8 vp;
#pragma unroll
      for (int e = 0; e < 8; ++e) vp[e] = (short)f2bf(pv[cc][e]);
      *(bf16x8*)(smVt + vt * 8192 + swz(v_dcol, vkc << 4)) = vp;
    }
  };

  // ---- fb = min{k : mask[b,k]=1} (block-uniform) ----
  if (tid == 0) sfb = S_LEN;
  __syncthreads();
  PREFETCH(0);
  {
    int loc = S_LEN;
    for (int k = tid; k < S_LEN; k += 1024)
      if (Mb[k]) { loc = k; break; }
    if (loc < S_LEN) atomicMin(&sfb, loc);
  }
  __syncthreads();
  const int fb = sfb;

  // ---- Q fragments (A operand: row = lane&15; slots = contiguous d) ----
  bf16x8 qf[2];
  {
    const float* qp = Qb + (size_t)(q0 + g * 16 + p) * DH + h * 8;
    const float4* q4a = (const float4*)(qp);
    const float4* q4b = (const float4*)(qp + 32);
    qf[0] = pack8(q4a[0], q4a[1]);
    qf[1] = pack8(q4b[0], q4b[1]);
  }

  f32x4 o[4];
  float m_r[4], l_r[4];
#pragma unroll
  for (int j = 0; j < 4; ++j)
#pragma unroll
    for (int e = 0; e < 4; ++e) o[j][e] = 0.f;
#pragma unroll
  for (int rr = 0; rr < 4; ++rr) { m_r[rr] = -INFINITY; l_r[rr] = 0.f; }

  const int qrb = q0 + g * 16 + h * 4;  // + rr => this lane's acc rows

  const int ns = (qt >> 2) + 1;         // ceil((qt+1)/4)
  for (int s = 0; s < ns; ++s) {
    __syncthreads();                    // (a) LDS free
    WRITE_LDS();
    const int j = (s << 2) + r;         // this wave's KV tile
    float pen[4];
#pragma unroll
    for (int t16 = 0; t16 < 4; ++t16)
      pen[t16] = pm[t16] ? 0.f : -NEGF; // consume pm before next PREFETCH
    if (s + 1 < ns) PREFETCH(s + 1);    // issue before barrier: fly across it
    __syncthreads();                    // (b) LDS ready

    if (j <= qt) {
      const int kv0 = j << 6;
      const unsigned char* myK  = smK  + r * 8192;
      const unsigned char* myVt = smVt + r * 8192;

      // ---- QK^T ----
      f32x4 acc[4];
#pragma unroll
      for (int t16 = 0; t16 < 4; ++t16) {
        f32x4 a;
#pragma unroll
        for (int e = 0; e < 4; ++e) a[e] = 0.f;
#pragma unroll
        for (int c = 0; c < 2; ++c) {
          bf16x8 kb = *(const bf16x8*)(myK + swz(t16 * 16 + p, c * 64 + h * 16));
          a = __builtin_amdgcn_mfma_f32_16x16x32_bf16(qf[c], kb, a, 0, 0, 0);
        }
        acc[t16] = a;
      }

      // ---- scores ----
      float sc[4][4];
#pragma unroll
      for (int t16 = 0; t16 < 4; ++t16) {
        const int key = kv0 + t16 * 16 + p;
#pragma unroll
        for (int rr = 0; rr < 4; ++rr) {
          float v = fmaf(acc[t16][rr], 0.125f, pen[t16]);
          if (key > qrb + rr) v -= NEGF;          // causal
          sc[t16][rr] = v;
        }
      }

      // ---- online softmax (phase-local partial) ----
      float alpha[4];
#pragma unroll
      for (int rr = 0; rr < 4; ++rr) {
        float v = fmaxf(fmaxf(sc[0][rr], sc[1][rr]), fmaxf(sc[2][rr], sc[3][rr]));
        v = fmaxf(v, __shfl_xor(v, 1));
        v = fmaxf(v, __shfl_xor(v, 2));
        v = fmaxf(v, __shfl_xor(v, 4));
        v = fmaxf(v, __shfl_xor(v, 8));
        const float mn = fmaxf(m_r[rr], v);
        alpha[rr] = __expf(m_r[rr] - mn);
        m_r[rr] = mn;
      }

      unsigned char* Pw = smP + (wid << 11);
      float rs[4] = {0.f, 0.f, 0.f, 0.f};
#pragma unroll
      for (int t16 = 0; t16 < 4; ++t16) {
#pragma unroll
        for (int rr = 0; rr < 4; ++rr) {
          float pv2 = __expf(sc[t16][rr] - m_r[rr]);
          rs[rr] += pv2;
          *(unsigned short*)(Pw + swz(h * 4 + rr, (t16 * 16 + p) << 1)) = f2bf(pv2);
        }
      }
#pragma unroll
      for (int rr = 0; rr < 4; ++rr) {
        float v = rs[rr];
        v += __shfl_xor(v, 1);
        v += __shfl_xor(v, 2);
        v += __shfl_xor(v, 4);
        v += __shfl_xor(v, 8);
        l_r[rr] = l_r[rr] * alpha[rr] + v;
      }
#pragma unroll
      for (int jj = 0; jj < 4; ++jj)
#pragma unroll
        for (int rr = 0; rr < 4; ++rr) o[jj][rr] *= alpha[rr];

      // same-wave P write -> P read: drain LDS, keep reads below
      asm volatile("s_waitcnt lgkmcnt(0)" ::: "memory");
      __builtin_amdgcn_sched_barrier(0);

      // ---- PV ----
      bf16x8 pf[2];
#pragma unroll
      for (int c = 0; c < 2; ++c)
        pf[c] = *(const bf16x8*)(Pw + swz(p, c * 64 + h * 16));
#pragma unroll
      for (int jj = 0; jj < 4; ++jj)
#pragma unroll
        for (int c = 0; c < 2; ++c) {
          bf16x8 vb = *(const bf16x8*)(myVt + swz(jj * 16 + p, c * 64 + h * 16));
          o[jj] = __builtin_amdgcn_mfma_f32_16x16x32_bf16(pf[c], vb, o[jj], 0, 0, 0);
        }
    }
  }

  // ---- merge 4 phase-partials per q-group. Layout [elem][wid][lane]:
  // lane-stride 4B -> conflict-free scalar stores/loads.
  __syncthreads();                       // all compute done; smem reusable
  {
    float* wb = (float*)smem + wid * 64 + lane;
#pragma unroll
    for (int rr = 0; rr < 4; ++rr) {
      wb[(rr)     * 1024] = m_r[rr];
      wb[(4 + rr) * 1024] = l_r[rr];
    }
#pragma unroll
    for (int jj = 0; jj < 4; ++jj)
#pragma unroll
      for (int rr = 0; rr < 4; ++rr)
        wb[(8 + jj * 4 + rr) * 1024] = o[jj][rr];
  }
  __syncthreads();

  if (r == 0) {
    const float* w0 = (float*)smem + (wid + 0) * 64 + lane;
    const float* w1 = (float*)smem + (wid + 1) * 64 + lane;
    const float* w2 = (float*)smem + (wid + 2) * 64 + lane;
    const float* w3 = (float*)smem + (wid + 3) * 64 + lane;
    float* Ob = O + ((size_t)b * S_LEN) * DH;
#pragma unroll
    for (int rr = 0; rr < 4; ++rr) {
      if (qrb + rr < fb) continue;       // degen row: written below
      const float M = fmaxf(fmaxf(w0[rr * 1024], w1[rr * 1024]),
                            fmaxf(w2[rr * 1024], w3[rr * 1024]));
      const float e0 = __expf(w0[rr * 1024] - M), e1 = __expf(w1[rr * 1024] - M);
      const float e2 = __expf(w2[rr * 1024] - M), e3 = __expf(w3[rr * 1024] - M);
      const float L = w0[(4 + rr) * 1024] * e0 + w1[(4 + rr) * 1024] * e1 +
                      w2[(4 + rr) * 1024] * e2 + w3[(4 + rr) * 1024] * e3;
      const float inv = 1.f / L;
#pragma unroll
      for (int jj = 0; jj < 4; ++jj) {
        const int e = (8 + jj * 4 + rr) * 1024;
        const float num = w0[e] * e0 + w1[e] * e1 + w2[e] * e2 + w3[e] * e3;
        Ob[(size_t)(qrb + rr) * DH + jj * 16 + p] = num * inv;
      }
    }
  }

  // ---- degenerate rows: q ≡ qt (mod 64), q < fb ----
  for (int dq = qt; dq < fb; dq += 64) {
    __syncthreads();                     // merge reads done; smem reusable
    float* ssc   = (float*)smem;         // [4096] exp-scores
    float* sq    = (float*)smem + 4096;  // [64] q-vector
    float* spart = (float*)smem + 4160;  // [16][64] wave PV partials
    float* sred  = (float*)smem + 5184;  // [32] reduction scratch
    if (tid < 64) sq[tid] = Qb[(size_t)dq * DH + tid];
    __syncthreads();

    float lmax = -1e30f;
    for (int k = tid; k < S_LEN; k += 1024) {
      float s = -1e30f;
      if (k <= dq || Mb[k]) {
        const float4* kp = (const float4*)(Kb + (size_t)k * DH);
        float acc = 0.f;
#pragma unroll
        for (int d4 = 0; d4 < 16; ++d4) {
          const float4 kv = kp[d4];
          acc += sq[d4 * 4 + 0] * kv.x + sq[d4 * 4 + 1] * kv.y +
                 sq[d4 * 4 + 2] * kv.z + sq[d4 * 4 + 3] * kv.w;
        }
        s = acc * 0.125f;
      }
      ssc[k] = s;
      lmax = fmaxf(lmax, s);
    }
#pragma unroll
    for (int o2 = 32; o2; o2 >>= 1) lmax = fmaxf(lmax, __shfl_xor(lmax, o2));
    if (lane == 0) sred[wid] = lmax;
    __syncthreads();
    float gmax = sred[0];
#pragma unroll
    for (int i = 1; i < 16; ++i) gmax = fmaxf(gmax, sred[i]);

    float lsum = 0.f;
    for (int k = tid; k < S_LEN; k += 1024) {
      const float e = (ssc[k] > -1e29f) ? __expf(ssc[k] - gmax) : 0.f;
      ssc[k] = e;
      lsum += e;
    }
#pragma unroll
    for (int o2 = 32; o2; o2 >>= 1) lsum += __shfl_xor(lsum, o2);
    if (lane == 0) sred[16 + wid] = lsum;
    __syncthreads();
    float gsum = 0.f;
#pragma unroll
    for (int i = 0; i < 16; ++i) gsum += sred[16 + i];
    const float inv = 1.f / gsum;

    {
      const int k0d = wid << 8;
      float a0 = 0.f, a1 = 0.f, a2 = 0.f, a3 = 0.f;
      for (int kk = 0; kk < 256; kk += 4) {
        a0 = fmaf(ssc[k0d + kk + 0], Vb[(size_t)(k0d + kk + 0) * DH + lane], a0);
        a1 = fmaf(ssc[k0d + kk + 1], Vb[(size_t)(k0d + kk + 1) * DH + lane], a1);
        a2 = fmaf(ssc[k0d + kk + 2], Vb[(size_t)(k0d + kk + 2) * DH + lane], a2);
        a3 = fmaf(ssc[k0d + kk + 3], Vb[(size_t)(k0d + kk + 3) * DH + lane], a3);
      }
      spart[wid * 64 + lane] = (a0 + a1) + (a2 + a3);
    }
    __syncthreads();
    if (tid < 64) {
      float num = 0.f;
#pragma unroll
      for (int i = 0; i < 16; ++i) num += spart[i * 64 + tid];
      O[((size_t)b * S_LEN + dq) * DH + tid] = num * inv;
    }
  }
}

extern "C" void kernel_launch(void* const* d_in, const int* in_sizes, int n_in,
                              void* d_out, int out_size, void* d_ws, size_t ws_size,
                              hipStream_t stream) {
  const float* Q = (const float*)d_in[0];
  const float* K = (const float*)d_in[1];
  const float* V = (const float*)d_in[2];
  const int*   M = (const int*)d_in[3];
  float* O = (float*)d_out;
  attn_fwd<<<dim3(4 * (S_LEN / 64)), dim3(1024), 0, stream>>>(Q, K, V, M, O);
}